// Round 2
// 189.816 us; speedup vs baseline: 1.0018x; 1.0018x over previous
//
#include <hip/hip_runtime.h>

#define EMB 2048
#define NC 4
#define NROWS 16384
#define SCALE_S 16.0f

// One wave (64 lanes) per row. Block = 256 threads = 4 waves.
// Each wave processes ROWS_PER_WAVE rows, software-pipelined: row r+1's
// global loads are issued before row r's compute+reduce, so ~8 KB/wave of
// HBM traffic stays in flight across the serial reduction chain.
// W (4 x 2048 fp32 = 32 KB) staged in LDS once per block (4 blocks/CU -> 128 KB).
#define ROWS_PER_WAVE 4
#define WAVES_PER_BLOCK 4
#define ROWS_PER_BLOCK (ROWS_PER_WAVE * WAVES_PER_BLOCK)   // 16

__global__ __launch_bounds__(256) void binary_head_kernel(
    const float* __restrict__ fea,
    const float* __restrict__ W,
    const float* __restrict__ bias,
    float* __restrict__ out)
{
    // W as float4: 4 classes x 512 float4 = 2048 float4 = 32 KB
    __shared__ float4 sW[NC * (EMB / 4)];

    const int tid = threadIdx.x;

    // Stage W -> LDS: 2048 float4 by 256 threads = 8 each, coalesced.
    const float4* W4 = (const float4*)W;
#pragma unroll
    for (int i = 0; i < 8; ++i) {
        sW[i * 256 + tid] = W4[i * 256 + tid];
    }

    const int wave = tid >> 6;
    const int lane = tid & 63;

    // Preload bias once (all lanes load b[lane&3]; only lanes 0..3 use it).
    const float bval = bias[lane & (NC - 1)];

    const float4* fea4 = (const float4*)fea;
    const int rowBase = blockIdx.x * ROWS_PER_BLOCK + wave * ROWS_PER_WAVE;

    // Prologue: issue row 0's loads BEFORE the barrier so they overlap
    // the wait on W staging.
    float4 x[8], xn[8];
    {
        const float4* frow = fea4 + (size_t)rowBase * (EMB / 4);
#pragma unroll
        for (int j = 0; j < 8; ++j) {
            x[j] = frow[j * 64 + lane];
        }
    }

    __syncthreads();   // W visible to all waves

#pragma unroll
    for (int r = 0; r < ROWS_PER_WAVE; ++r) {
        // Prefetch next row while computing/reducing this one.
        if (r + 1 < ROWS_PER_WAVE) {
            const float4* fnext = fea4 + (size_t)(rowBase + r + 1) * (EMB / 4);
#pragma unroll
            for (int j = 0; j < 8; ++j) {
                xn[j] = fnext[j * 64 + lane];
            }
        }

        float ss = 0.0f, d0 = 0.0f, d1 = 0.0f, d2 = 0.0f, d3 = 0.0f;
#pragma unroll
        for (int j = 0; j < 8; ++j) {
            const float4 v = x[j];
            const int col = j * 64 + lane;

            ss += v.x * v.x + v.y * v.y + v.z * v.z + v.w * v.w;

            const float4 w0 = sW[0 * 512 + col];
            d0 += v.x * w0.x + v.y * w0.y + v.z * w0.z + v.w * w0.w;
            const float4 w1 = sW[1 * 512 + col];
            d1 += v.x * w1.x + v.y * w1.y + v.z * w1.z + v.w * w1.w;
            const float4 w2 = sW[2 * 512 + col];
            d2 += v.x * w2.x + v.y * w2.y + v.z * w2.z + v.w * w2.w;
            const float4 w3 = sW[3 * 512 + col];
            d3 += v.x * w3.x + v.y * w3.y + v.z * w3.z + v.w * w3.w;
        }

        // Wave-wide butterfly reduction (64 lanes) for all 5 partials.
        // 5 independent chains -> depth is 6 shuffle latencies, not 30.
#pragma unroll
        for (int m = 1; m < 64; m <<= 1) {
            ss += __shfl_xor(ss, m, 64);
            d0 += __shfl_xor(d0, m, 64);
            d1 += __shfl_xor(d1, m, 64);
            d2 += __shfl_xor(d2, m, 64);
            d3 += __shfl_xor(d3, m, 64);
        }

        const int row = rowBase + r;
        if (lane < NC) {
            const float d = (lane == 0) ? d0 : (lane == 1) ? d1 : (lane == 2) ? d2 : d3;
            const float inv = rsqrtf(ss);
            out[row * NC + lane] = (d * inv + bval) * SCALE_S;
        }

        // Rotate pipeline registers (dead on last iteration; compiler elides).
        if (r + 1 < ROWS_PER_WAVE) {
#pragma unroll
            for (int j = 0; j < 8; ++j) {
                x[j] = xn[j];
            }
        }
    }
}

extern "C" void kernel_launch(void* const* d_in, const int* in_sizes, int n_in,
                              void* d_out, int out_size, void* d_ws, size_t ws_size,
                              hipStream_t stream) {
    const float* fea  = (const float*)d_in[0];
    const float* W    = (const float*)d_in[1];
    const float* bias = (const float*)d_in[2];
    float* out = (float*)d_out;

    const int grid = NROWS / ROWS_PER_BLOCK;  // 16384 / 16 = 1024
    binary_head_kernel<<<grid, 256, 0, stream>>>(fea, W, bias, out);
}